// Round 9
// baseline (139.221 us; speedup 1.0000x reference)
//
#include <hip/hip_runtime.h>
#include <math.h>

typedef short bf16x8 __attribute__((ext_vector_type(8)));
typedef float f32x4 __attribute__((ext_vector_type(4)));

#define BDIM 256    // prep + fallback attn
#define ADIM 512    // wide attn (8 waves)
constexpr int B_ = 2, H_ = 16, L_ = 1024, D_ = 64, LMAX_ = 2048;
constexpr int BH_ = B_ * H_;
constexpr float PI_F = 3.14159265358979323846f;

// ws float offsets
constexpr int WS_SVP = 0;                    // fp32 [2][32][64][16] SumV partials ([d][q])
constexpr int WS_KBR = 65536;                // u16 [32][1024][64]
constexpr int WS_KBI = WS_KBR + 1048576;
constexpr int WS_VTR = WS_KBI + 1048576;     // u16 [32][64][1024]
constexpr int WS_VTI = WS_VTR + 1048576;

__device__ __forceinline__ unsigned short f2b(float x) {
    union { float f; unsigned u; } v; v.f = x;
    return (unsigned short)((v.u + 0x8000u) >> 16);
}
__device__ __forceinline__ float b2f(unsigned short x) {
    union { unsigned u; float f; } v; v.u = ((unsigned)x) << 16;
    return v.f;
}
__device__ __forceinline__ unsigned pk2(float a, float b) {
    union { float f; unsigned u; } va, vb; va.f = a; vb.f = b;
    return ((va.u + 0x8000u) >> 16) | ((vb.u + 0x8000u) & 0xFFFF0000u);
}
__device__ __forceinline__ uint4 pack4(const float4& a, const float4& b) {
    return make_uint4(pk2(a.x, a.y), pk2(a.z, a.w), pk2(b.x, b.y), pk2(b.z, b.w));
}
__device__ __forceinline__ unsigned cvtpk(float lo, float hi) {
    unsigned r;
    asm("v_cvt_pk_bf16_f32 %0, %1, %2" : "=v"(r) : "v"(lo), "v"(hi));
    return r;
}
__device__ __forceinline__ float vsqrt(float x) {
    float r;
    asm("v_sqrt_f32 %0, %1" : "=v"(r) : "v"(x));
    return r;
}

#define MFMA(a, b, c) __builtin_amdgcn_mfma_f32_16x16x32_bf16((a), (b), (c), 0, 0, 0)

__device__ __forceinline__ float a_val(int s, int l, float4 invn) {
    const float fr = (s == 0) ? 1.0f : (s == 1) ? 0.5f : (s == 2) ? 0.25f : 0.1f;
    const float iv = (s == 0) ? invn.x : (s == 1) ? invn.y : (s == 2) ? invn.z : invn.w;
    float t = (2.0f * PI_F * fr / (float)(LMAX_ - 1)) * (float)l;
    float m2 = 3.0f + 2.0f * cosf(t) + 2.0f * cosf(0.5f * t) + 2.0f * cosf(1.5f * t);
    return sqrtf(fmaxf(m2, 0.0f)) * iv;
}

// ---------------- prep: K->bf16, V->V^T bf16, SumV partials ----------------
__global__ __launch_bounds__(BDIM)
void prep_kernel(const float* __restrict__ Kr, const float* __restrict__ Ki,
                 const float* __restrict__ Vr, const float* __restrict__ Vi,
                 float* __restrict__ ws) {
    const int tid = threadIdx.x;
    const int blk = blockIdx.x;
    unsigned short* KbR = (unsigned short*)(ws + WS_KBR);
    unsigned short* KbI = (unsigned short*)(ws + WS_KBI);
    unsigned short* VtR = (unsigned short*)(ws + WS_VTR);
    unsigned short* VtI = (unsigned short*)(ws + WS_VTI);

    if (blk < 256) {
        const int comp = blk >> 7;
        const float* src = comp ? Ki : Kr;
        unsigned short* dst = comp ? KbI : KbR;
        size_t b0 = (size_t)(blk & 127) * 16384;
#pragma unroll
        for (int i = 0; i < 4; ++i) {
            size_t e = b0 + (size_t)(i * 256 + tid) * 16;
            float4 x0 = *(const float4*)(src + e);
            float4 x1 = *(const float4*)(src + e + 4);
            float4 x2 = *(const float4*)(src + e + 8);
            float4 x3 = *(const float4*)(src + e + 12);
            *(uint4*)(dst + e) = pack4(x0, x1);
            *(uint4*)(dst + e + 8) = pack4(x2, x3);
        }
    } else {
        // sT stride 70 (35 dwords == 3 mod 32): conflict-free writes, ~2-way reads
        __shared__ unsigned short sT[64 * 70];
        __shared__ float sRed[4 * 64];
        const int vb = blk - 256;
        const int comp = vb & 1, mt = (vb >> 1) & 15, bh = vb >> 5;
        const int m0 = mt * 64;
        const float* src = (comp ? Vi : Vr) + (size_t)bh * 65536 + (size_t)m0 * 64;
        unsigned short* dstA = (comp ? VtI : VtR) + (size_t)bh * 65536;
#pragma unroll
        for (int i = 0; i < 4; ++i) {
            int e = i * 256 + tid;
            int m = e >> 4, d4 = (e & 15) * 4;
            float4 x = *(const float4*)(src + (size_t)m * 64 + d4);
            *(uint2*)&sT[m * 70 + d4] = make_uint2(pk2(x.x, x.y), pk2(x.z, x.w));
        }
        {
            int d = tid & 63, grp = tid >> 6;
            float s = 0.0f;
#pragma unroll
            for (int k = 0; k < 16; ++k) s += src[(size_t)(grp * 16 + k) * 64 + d];
            sRed[grp * 64 + d] = s;
        }
        __syncthreads();
        {
            int d = tid >> 2, ms = (tid & 3) * 16;
            unsigned short v[16];
#pragma unroll
            for (int k = 0; k < 16; ++k) v[k] = sT[(ms + k) * 70 + d];
            unsigned short* dst = dstA + (size_t)d * 1024 + m0 + ms;
            *(uint4*)dst = make_uint4((unsigned)v[0] | ((unsigned)v[1] << 16),
                                      (unsigned)v[2] | ((unsigned)v[3] << 16),
                                      (unsigned)v[4] | ((unsigned)v[5] << 16),
                                      (unsigned)v[6] | ((unsigned)v[7] << 16));
            *(uint4*)(dst + 8) = make_uint4((unsigned)v[8] | ((unsigned)v[9] << 16),
                                            (unsigned)v[10] | ((unsigned)v[11] << 16),
                                            (unsigned)v[12] | ((unsigned)v[13] << 16),
                                            (unsigned)v[14] | ((unsigned)v[15] << 16));
        }
        if (tid < 64)
            ws[WS_SVP + comp * 32768 + bh * 1024 + tid * 16 + mt] =
                sRed[tid] + sRed[64 + tid] + sRed[128 + tid] + sRed[192 + tid];
    }
}

// ---------------- staging / fragment helpers ----------------
__device__ __forceinline__ void stage64s(const unsigned short* g0, int stride,
                                         unsigned short* lds, int w, int lane) {
#pragma unroll
    for (int i = 0; i < 2; ++i) {
        int c = w * 2 + i;
        int lrow = c * 8 + (lane >> 3);
        int lg = (lane & 7) ^ (lrow & 7);
        const unsigned short* src = g0 + (size_t)lrow * stride + lg * 8;
        __builtin_amdgcn_global_load_lds(
            (const __attribute__((address_space(1))) void*)src,
            (__attribute__((address_space(3))) void*)(lds + c * 512), 16, 0, 0);
    }
}
__device__ __forceinline__ bf16x8 ldfrag(const unsigned short* b, int row, int g) {
    return *(const bf16x8*)&b[row * 64 + ((g ^ (row & 7)) << 3)];
}

// ---------------- wide attention: PV software-pipelined one tile behind ----------------
// Round-7 left ~47% idle with sync minimal -> dependency-latency bound:
// QK^T = two 4-deep MFMA chains/wave, PV (the ILP-rich region, 8x 2-deep)
// runs serially after it. Pipeline: iter mt computes QK^T(mt) -> sE[mt&1]
// AND PV(mt-1) from sE[(mt-1)&1], interleaved per-ct phase (8 QK^T + 4 PV
// MFMAs -> ~8 chains/wave). sE double-buffered; V triple-buffered (staging
// V(mt+1) into slot (mt+1)%3 never collides with PV(mt-1)'s slot (mt-1)%3).
// QK^T accumulators split 4->2x2-deep (aRa/aRb, aIa/aIb) for extra ILP.
constexpr int OFF_DEN = 0;                        // f32 [4][128]      2048 B
constexpr int OFF_K0  = 2048;                     // u16 [2][4096]    16384 B
constexpr int OFF_K1  = OFF_K0 + 16384;
constexpr int OFF_V0  = OFF_K1 + 16384;           // u16 [3][4096]    24576 B
constexpr int OFF_V1  = OFF_V0 + 24576;
constexpr int OFF_E   = OFF_V1 + 24576;           // u16 [2][8192]    32768 B
constexpr int OFF_MG  = OFF_E + 32768;            // u16 [8192]       16384 B
constexpr int OFF_AMB = OFF_MG + 16384;           // u16 [4*1032]      8256 B
constexpr int SMEM_BYTES = OFF_AMB + 8256;        // = 141376

__global__ __launch_bounds__(ADIM, 2)
void attn_kernel_w(const float* __restrict__ Qr, const float* __restrict__ Qi,
                   const float* __restrict__ ws, float* __restrict__ out, float4 invn) {
    extern __shared__ char smem[];
    float* sDen = (float*)(smem + OFF_DEN);
    unsigned short* sK0 = (unsigned short*)(smem + OFF_K0);   // [2][4096]
    unsigned short* sK1 = (unsigned short*)(smem + OFF_K1);
    unsigned short* sV0 = (unsigned short*)(smem + OFF_V0);   // [3][4096]
    unsigned short* sV1 = (unsigned short*)(smem + OFF_V1);
    unsigned short* sE  = (unsigned short*)(smem + OFF_E);    // [2][128*64]
    unsigned short* sMg = (unsigned short*)(smem + OFF_MG);
    unsigned short* sAmb = (unsigned short*)(smem + OFF_AMB); // stride 1032

    const int tid = threadIdx.x;
    const int lane = tid & 63;
    const int w = tid >> 6;                     // 0..7
    const int lo16 = lane & 15;
    const int quad = lane >> 4;
    const int blk = blockIdx.x;                 // 256 blocks
    const int bh = (blk & 7) * 4 + (blk >> 6);  // XCD-clustered: 4 bh per XCD
    const int qt = (blk >> 3) & 7;
    const int l0 = qt * 128;
    const size_t base = (size_t)bh * (L_ * D_);

    const unsigned short* gKr = (const unsigned short*)(ws + WS_KBR) + (size_t)bh * 65536;
    const unsigned short* gKi = (const unsigned short*)(ws + WS_KBI) + (size_t)bh * 65536;
    const unsigned short* gVr = (const unsigned short*)(ws + WS_VTR) + (size_t)bh * 65536;
    const unsigned short* gVi = (const unsigned short*)(ws + WS_VTI) + (size_t)bh * 65536;

    // prologue: tile-0 staging (wave-split) overlaps amb trig + Q packing
    if (w < 4) {
        stage64s(gKr, 64, sK0, w, lane);
        stage64s(gKi, 64, sK1, w, lane);
    } else {
        stage64s(gVr, 1024, sV0, w - 4, lane);
        stage64s(gVi, 1024, sV1, w - 4, lane);
    }

    // amb table (a/8 bf16)
    for (int e = tid; e < 4096; e += ADIM) {
        int s = e >> 10, l = e & 1023;
        sAmb[s * 1032 + l] = f2b(a_val(s, l, invn) * 0.125f);
    }

    // Q fragments
    bf16x8 fQr0, fQr1, fQi0, fQi1, fnQi0, fnQi1;
    {
        const int ql = l0 + w * 16 + lo16;
        const float* qr = Qr + base + (size_t)ql * 64;
        const float* qi = Qi + base + (size_t)ql * 64;
        float4 a0 = *(const float4*)(qr + quad * 8);
        float4 a1 = *(const float4*)(qr + quad * 8 + 4);
        float4 b0 = *(const float4*)(qr + 32 + quad * 8);
        float4 b1 = *(const float4*)(qr + 32 + quad * 8 + 4);
        *(uint4*)&fQr0 = pack4(a0, a1);
        *(uint4*)&fQr1 = pack4(b0, b1);
        a0 = *(const float4*)(qi + quad * 8);
        a1 = *(const float4*)(qi + quad * 8 + 4);
        b0 = *(const float4*)(qi + 32 + quad * 8);
        b1 = *(const float4*)(qi + 32 + quad * 8 + 4);
        *(uint4*)&fQi0 = pack4(a0, a1);
        *(uint4*)&fQi1 = pack4(b0, b1);
        uint4 t0 = *(uint4*)&fQi0, t1 = *(uint4*)&fQi1;
        t0.x ^= 0x80008000u; t0.y ^= 0x80008000u; t0.z ^= 0x80008000u; t0.w ^= 0x80008000u;
        t1.x ^= 0x80008000u; t1.y ^= 0x80008000u; t1.z ^= 0x80008000u; t1.w ^= 0x80008000u;
        *(uint4*)&fnQi0 = t0; *(uint4*)&fnQi1 = t1;
    }

    __syncthreads();   // full drain: tile-0 + sAmb visible

    bf16x8 uf1a = (bf16x8){0, 0, 0, 0, 0, 0, 0, 0};
    uf1a[0] = (short)f2b(b2f(sAmb[quad * 1032 + (l0 + w * 16 + lo16)]) *
                         (1.0f / 128.0f));

    f32x4 accM1 = (f32x4){0.f, 0.f, 0.f, 0.f};
    f32x4 aOutR[4], aOutI[4];
#pragma unroll
    for (int dt = 0; dt < 4; ++dt) {
        aOutR[dt] = (f32x4){0.f, 0.f, 0.f, 0.f};
        aOutI[dt] = (f32x4){0.f, 0.f, 0.f, 0.f};
    }

    const int lrow_w = w * 16 + lo16;   // this wave's private row in sE/sMg

    // QK^T for tile mt, ct phase -> writes sE[ecur], sMg
#define QKT_PHASE(cK0_, cK1_, eDst_, m0_, ct_)                                     \
    {                                                                              \
        const int mrow = (ct_) * 16 + lo16;                                        \
        bf16x8 kr0 = ldfrag((cK0_), mrow, quad), kr1 = ldfrag((cK0_), mrow, quad + 4); \
        bf16x8 ki0 = ldfrag((cK1_), mrow, quad), ki1 = ldfrag((cK1_), mrow, quad + 4); \
        f32x4 z = (f32x4){0.f, 0.f, 0.f, 0.f};                                     \
        __builtin_amdgcn_s_setprio(1);                                             \
        f32x4 aRa = MFMA(kr0, fQr0, z);  aRa = MFMA(ki0, fnQi0, aRa);              \
        f32x4 aRb = MFMA(kr1, fQr1, z);  aRb = MFMA(ki1, fnQi1, aRb);              \
        f32x4 aIa = MFMA(ki0, fQr0, z);  aIa = MFMA(kr0, fQi0, aIa);               \
        f32x4 aIb = MFMA(ki1, fQr1, z);  aIb = MFMA(kr1, fQi1, aIb);               \
        __builtin_amdgcn_s_setprio(0);                                             \
        f32x4 aR = aRa + aRb, aI = aIa + aIb;                                      \
        float mg0 = vsqrt(fmaf(aR[0], aR[0], aI[0] * aI[0]));                      \
        float mg1 = vsqrt(fmaf(aR[1], aR[1], aI[1] * aI[1]));                      \
        float mg2 = vsqrt(fmaf(aR[2], aR[2], aI[2] * aI[2]));                      \
        float mg3 = vsqrt(fmaf(aR[3], aR[3], aI[3] * aI[3]));                      \
        bf16x8 bf1 = (bf16x8){0, 0, 0, 0, 0, 0, 0, 0};                             \
        bf1[0] = (short)sAmb[quad * 1032 + (m0_) + (ct_) * 16 + lo16];             \
        f32x4 a1 = MFMA(bf1, uf1a, z);                                             \
        float p0 = mg0 * a1[0], p1 = mg1 * a1[1];                                  \
        float p2 = mg2 * a1[2], p3 = mg3 * a1[3];                                  \
        int gph = ((ct_) * 2 + (quad >> 1)) ^ (lrow_w & 7);                        \
        *(uint2*)&(eDst_)[lrow_w * 64 + gph * 8 + (quad & 1) * 4] =                \
            make_uint2(cvtpk(p0, p1), cvtpk(p2, p3));                              \
        *(uint2*)&sMg[lrow_w * 64 + gph * 8 + (quad & 1) * 4] =                    \
            make_uint2(cvtpk(mg0, mg1), cvtpk(mg2, mg3));                          \
    }

#define M1_STEP(m0_)                                                               \
    {                                                                              \
        bf16x8 mf0 = ldfrag(sMg, lrow_w, quad);                                    \
        bf16x8 mf1 = ldfrag(sMg, lrow_w, quad + 4);                                \
        bf16x8 b0 = (bf16x8){0, 0, 0, 0, 0, 0, 0, 0};                              \
        bf16x8 b1 = (bf16x8){0, 0, 0, 0, 0, 0, 0, 0};                              \
        if (lo16 < 4) {                                                            \
            b0 = *(const bf16x8*)&sAmb[lo16 * 1032 + (m0_) + quad * 8];            \
            b1 = *(const bf16x8*)&sAmb[lo16 * 1032 + (m0_) + 32 + quad * 8];       \
        }                                                                          \
        accM1 = MFMA(mf0, b0, accM1);                                              \
        accM1 = MFMA(mf1, b1, accM1);                                              \
    }

#define PV_PHASE(pV0_, pV1_, pa0_, pa1_, dt_)                                      \
    {                                                                              \
        int dr = (dt_) * 16 + lo16;                                                \
        bf16x8 vr0 = ldfrag((pV0_), dr, quad), vr1 = ldfrag((pV0_), dr, quad + 4); \
        bf16x8 vi0 = ldfrag((pV1_), dr, quad), vi1 = ldfrag((pV1_), dr, quad + 4); \
        __builtin_amdgcn_s_setprio(1);                                             \
        aOutR[dt_] = MFMA((pa0_), vr0, aOutR[dt_]);                                \
        aOutR[dt_] = MFMA((pa1_), vr1, aOutR[dt_]);                                \
        aOutI[dt_] = MFMA((pa0_), vi0, aOutI[dt_]);                                \
        aOutI[dt_] = MFMA((pa1_), vi1, aOutI[dt_]);                                \
        __builtin_amdgcn_s_setprio(0);                                             \
    }

    // ---- peeled iteration 0: QK^T(0) only ----
    {
        if (w < 4) {
            stage64s(gKr + (size_t)64 * 64, 64, sK0 + 4096, w, lane);
            stage64s(gKi + (size_t)64 * 64, 64, sK1 + 4096, w, lane);
        } else {
            stage64s(gVr + 64, 1024, sV0 + 4096, w - 4, lane);
            stage64s(gVi + 64, 1024, sV1 + 4096, w - 4, lane);
        }
        QKT_PHASE(sK0, sK1, sE, 0, 0)
        QKT_PHASE(sK0, sK1, sE, 0, 1)
        QKT_PHASE(sK0, sK1, sE, 0, 2)
        QKT_PHASE(sK0, sK1, sE, 0, 3)
        M1_STEP(0)
        asm volatile("s_waitcnt vmcnt(0)" ::: "memory");
        __builtin_amdgcn_s_barrier();
    }

    // ---- main loop: mt = 1..15, PV runs one tile behind ----
#pragma unroll 1
    for (int mt = 1; mt < 16; ++mt) {
        const int m0 = mt * 64;
        const int cur = mt & 1;
        const int vprev = (mt - 1) % 3;
        if (mt < 15) {
            const int vnext = (mt + 1) % 3;
            if (w < 4) {
                stage64s(gKr + (size_t)(m0 + 64) * 64, 64, sK0 + (cur ^ 1) * 4096, w, lane);
                stage64s(gKi + (size_t)(m0 + 64) * 64, 64, sK1 + (cur ^ 1) * 4096, w, lane);
            } else {
                stage64s(gVr + m0 + 64, 1024, sV0 + vnext * 4096, w - 4, lane);
                stage64s(gVi + m0 + 64, 1024, sV1 + vnext * 4096, w - 4, lane);
            }
        }
        const unsigned short* cK0 = sK0 + cur * 4096;
        const unsigned short* cK1 = sK1 + cur * 4096;
        const unsigned short* pV0 = sV0 + vprev * 4096;
        const unsigned short* pV1 = sV1 + vprev * 4096;
        unsigned short* eCur = sE + cur * 8192;
        const unsigned short* ePrev = sE + (cur ^ 1) * 8192;

        // previous tile's P' fragments (wave-private, no sync needed)
        bf16x8 pa0 = ldfrag(ePrev, lrow_w, quad);
        bf16x8 pa1 = ldfrag(ePrev, lrow_w, quad + 4);

        // interleaved phases: QK^T(mt, ct) + PV(mt-1, dt=ct)
        QKT_PHASE(cK0, cK1, eCur, m0, 0)
        PV_PHASE(pV0, pV1, pa0, pa1, 0)
        QKT_PHASE(cK0, cK1, eCur, m0, 1)
        PV_PHASE(pV0, pV1, pa0, pa1, 1)
        QKT_PHASE(cK0, cK1, eCur, m0, 2)
        PV_PHASE(pV0, pV1, pa0, pa1, 2)
        QKT_PHASE(cK0, cK1, eCur, m0, 3)
        PV_PHASE(pV0, pV1, pa0, pa1, 3)
        M1_STEP(m0)

        asm volatile("s_waitcnt vmcnt(0)" ::: "memory");
        __builtin_amdgcn_s_barrier();
    }

    // ---- epilogue PV(15): sE[1], V slot 15%3=0 (published, never overwritten) ----
    {
        const unsigned short* pV0 = sV0;
        const unsigned short* pV1 = sV1;
        const unsigned short* ePrev = sE + 8192;
        bf16x8 pa0 = ldfrag(ePrev, lrow_w, quad);
        bf16x8 pa1 = ldfrag(ePrev, lrow_w, quad + 4);
        PV_PHASE(pV0, pV1, pa0, pa1, 0)
        PV_PHASE(pV0, pV1, pa0, pa1, 1)
        PV_PHASE(pV0, pV1, pa0, pa1, 2)
        PV_PHASE(pV0, pV1, pa0, pa1, 3)
    }

    // exact denominators (same-wave rows; no barrier needed)
    if (lo16 < 4) {
#pragma unroll
        for (int reg = 0; reg < 4; ++reg) {
            int r = w * 16 + quad * 4 + reg;
            float alv = b2f(sAmb[lo16 * 1032 + (l0 + r)]) * 8.0f;
            sDen[lo16 * 128 + r] = 1.0f / (1024.0f + alv * accM1[reg]);
        }
    }
    float cden[4];
#pragma unroll
    for (int reg = 0; reg < 4; ++reg) {
        int r = w * 16 + quad * 4 + reg;   // same-wave LDS read
        cden[reg] = sDen[r] + sDen[128 + r] + sDen[256 + r] + sDen[384 + r];
    }

    // expert eC
    const float cE = rsqrtf(2048.0f) * rsqrtf(24.0f);
    float eRr[4], eRi[4];
#pragma unroll
    for (int reg = 0; reg < 4; ++reg) {
        int lrow = l0 + w * 16 + quad * 4 + reg;
        float tl = (2.0f * PI_F / (float)(LMAX_ - 1)) * (float)lrow;
        float s1, c1;
        __sincosf(0.1f * tl, &s1, &c1);
        const float W[10] = {1.f, 2.f, 3.f, 3.f, 3.f, 3.f, 3.f, 3.f, 2.f, 1.f};
        float cr = c1, ci = s1;
        float er = W[0] * cr, ei = W[0] * ci;
#pragma unroll
        for (int k = 1; k < 10; ++k) {
            float nr = cr * c1 - ci * s1;
            float ni = cr * s1 + ci * c1;
            cr = nr; ci = ni;
            er = fmaf(W[k], cr, er);
            ei = fmaf(W[k], ci, ei);
        }
        eRr[reg] = er * cE;
        eRi[reg] = ei * cE;
    }

    const size_t ooff = (size_t)BH_ * L_ * D_;
#pragma unroll
    for (int dt = 0; dt < 4; ++dt) {
        int d = dt * 16 + lo16;
        const float* svp = ws + WS_SVP + bh * 1024 + (size_t)d * 16;
        float4 r0 = *(const float4*)(svp);
        float4 r1 = *(const float4*)(svp + 4);
        float4 r2 = *(const float4*)(svp + 8);
        float4 r3 = *(const float4*)(svp + 12);
        float svr = (r0.x + r0.y + r0.z + r0.w) + (r1.x + r1.y + r1.z + r1.w) +
                    (r2.x + r2.y + r2.z + r2.w) + (r3.x + r3.y + r3.z + r3.w);
        const float* svq = svp + 32768;
        r0 = *(const float4*)(svq);
        r1 = *(const float4*)(svq + 4);
        r2 = *(const float4*)(svq + 8);
        r3 = *(const float4*)(svq + 12);
        float svi = (r0.x + r0.y + r0.z + r0.w) + (r1.x + r1.y + r1.z + r1.w) +
                    (r2.x + r2.y + r2.z + r2.w) + (r3.x + r3.y + r3.z + r3.w);
        float sp, cp;
        __sincosf((2.0f * PI_F / 64.0f) * (float)d, &sp, &cp);
#pragma unroll
        for (int reg = 0; reg < 4; ++reg) {
            int lrow = l0 + w * 16 + quad * 4 + reg;
            float numR = fmaf(cden[reg], svr, aOutR[dt][reg]) * 0.5f;
            float numI = fmaf(cden[reg], svi, aOutI[dt][reg]) * 0.5f;
            float epr = cp * eRr[reg] - sp * eRi[reg];
            float epi = sp * eRr[reg] + cp * eRi[reg];
            size_t o = base + (size_t)lrow * 64 + d;
            out[o] = numR * epr - numI * epi;
            out[o + ooff] = numR * epi + numI * epr;
        }
    }
#undef QKT_PHASE
#undef M1_STEP
#undef PV_PHASE
}

// ---------------- fallback: round-5 256-thr attention (verbatim) ----------------
__global__ __launch_bounds__(BDIM, 2)
void attn_kernel(const float* __restrict__ Qr, const float* __restrict__ Qi,
                 const float* __restrict__ ws, float* __restrict__ out, float4 invn) {
    __shared__ unsigned short sK0[2][4096], sK1[2][4096];
    __shared__ unsigned short sV0[4096], sV1[4096];
    __shared__ unsigned short sE[4096];
    __shared__ unsigned short sMg[4096];
    __shared__ unsigned short sAmb[4 * 1032];
    __shared__ float sDen[4 * 64];

    const int tid = threadIdx.x;
    const int lane = tid & 63;
    const int w = tid >> 6;
    const int lo16 = lane & 15;
    const int quad = lane >> 4;
    const int blk = blockIdx.x;
    const int bh = (blk & 7) * 4 + (blk >> 7);
    const int qt = (blk >> 3) & 15;
    const int l0 = qt * 64;
    const size_t base = (size_t)bh * (L_ * D_);

    const unsigned short* gKr = (const unsigned short*)(ws + WS_KBR) + (size_t)bh * 65536;
    const unsigned short* gKi = (const unsigned short*)(ws + WS_KBI) + (size_t)bh * 65536;
    const unsigned short* gVr = (const unsigned short*)(ws + WS_VTR) + (size_t)bh * 65536;
    const unsigned short* gVi = (const unsigned short*)(ws + WS_VTI) + (size_t)bh * 65536;

    stage64s(gKr, 64, sK0[0], w, lane);
    stage64s(gKi, 64, sK1[0], w, lane);

    for (int e = tid; e < 4096; e += BDIM) {
        int s = e >> 10, l = e & 1023;
        sAmb[s * 1032 + l] = f2b(a_val(s, l, invn) * 0.125f);
    }

    bf16x8 fQr0, fQr1, fQi0, fQi1, fnQi0, fnQi1;
    {
        const int ql = l0 + w * 16 + lo16;
        const float* qr = Qr + base + (size_t)ql * 64;
        const float* qi = Qi + base + (size_t)ql * 64;
        float4 a0 = *(const float4*)(qr + quad * 8);
        float4 a1 = *(const float4*)(qr + quad * 8 + 4);
        float4 b0 = *(const float4*)(qr + 32 + quad * 8);
        float4 b1 = *(const float4*)(qr + 32 + quad * 8 + 4);
        *(uint4*)&fQr0 = pack4(a0, a1);
        *(uint4*)&fQr1 = pack4(b0, b1);
        a0 = *(const float4*)(qi + quad * 8);
        a1 = *(const float4*)(qi + quad * 8 + 4);
        b0 = *(const float4*)(qi + 32 + quad * 8);
        b1 = *(const float4*)(qi + 32 + quad * 8 + 4);
        *(uint4*)&fQi0 = pack4(a0, a1);
        *(uint4*)&fQi1 = pack4(b0, b1);
        uint4 t0 = *(uint4*)&fQi0, t1 = *(uint4*)&fQi1;
        t0.x ^= 0x80008000u; t0.y ^= 0x80008000u; t0.z ^= 0x80008000u; t0.w ^= 0x80008000u;
        t1.x ^= 0x80008000u; t1.y ^= 0x80008000u; t1.z ^= 0x80008000u; t1.w ^= 0x80008000u;
        *(uint4*)&fnQi0 = t0; *(uint4*)&fnQi1 = t1;
    }

    __syncthreads();

    bf16x8 uf1a = (bf16x8){0, 0, 0, 0, 0, 0, 0, 0};
    uf1a[0] = (short)f2b(b2f(sAmb[quad * 1032 + (l0 + w * 16 + lo16)]) *
                         (1.0f / 128.0f));

    f32x4 accM1 = (f32x4){0.f, 0.f, 0.f, 0.f};
    f32x4 aOutR[4], aOutI[4];
#pragma unroll
    for (int dt = 0; dt < 4; ++dt) {
        aOutR[dt] = (f32x4){0.f, 0.f, 0.f, 0.f};
        aOutI[dt] = (f32x4){0.f, 0.f, 0.f, 0.f};
    }

#pragma unroll 1
    for (int mt = 0; mt < 16; ++mt) {
        const int m0 = mt * 64;
        const int cur = mt & 1;
        stage64s(gVr + m0, 1024, sV0, w, lane);
        stage64s(gVi + m0, 1024, sV1, w, lane);
        if (mt < 15) {
            stage64s(gKr + (size_t)(m0 + 64) * 64, 64, sK0[cur ^ 1], w, lane);
            stage64s(gKi + (size_t)(m0 + 64) * 64, 64, sK1[cur ^ 1], w, lane);
        }
        const unsigned short* cK0 = sK0[cur];
        const unsigned short* cK1 = sK1[cur];

#pragma unroll
        for (int ct = 0; ct < 4; ++ct) {
            const int mrow = ct * 16 + lo16;
            bf16x8 kr0 = ldfrag(cK0, mrow, quad), kr1 = ldfrag(cK0, mrow, quad + 4);
            bf16x8 ki0 = ldfrag(cK1, mrow, quad), ki1 = ldfrag(cK1, mrow, quad + 4);
            f32x4 aR = (f32x4){0.f, 0.f, 0.f, 0.f};
            f32x4 aI = (f32x4){0.f, 0.f, 0.f, 0.f};
            __builtin_amdgcn_s_setprio(1);
            aR = MFMA(kr0, fQr0, aR);  aR = MFMA(kr1, fQr1, aR);
            aR = MFMA(ki0, fnQi0, aR); aR = MFMA(ki1, fnQi1, aR);
            aI = MFMA(ki0, fQr0, aI);  aI = MFMA(ki1, fQr1, aI);
            aI = MFMA(kr0, fQi0, aI);  aI = MFMA(kr1, fQi1, aI);
            __builtin_amdgcn_s_setprio(0);
            float mg0 = vsqrt(fmaf(aR[0], aR[0], aI[0] * aI[0]));
            float mg1 = vsqrt(fmaf(aR[1], aR[1], aI[1] * aI[1]));
            float mg2 = vsqrt(fmaf(aR[2], aR[2], aI[2] * aI[2]));
            float mg3 = vsqrt(fmaf(aR[3], aR[3], aI[3] * aI[3]));
            bf16x8 bf1 = (bf16x8){0, 0, 0, 0, 0, 0, 0, 0};
            bf1[0] = (short)sAmb[quad * 1032 + m0 + ct * 16 + lo16];
            f32x4 z = (f32x4){0.f, 0.f, 0.f, 0.f};
            f32x4 a1 = MFMA(bf1, uf1a, z);
            float p0 = mg0 * a1[0], p1 = mg1 * a1[1];
            float p2 = mg2 * a1[2], p3 = mg3 * a1[3];
            int l = w * 16 + lo16;
            int gph = (ct * 2 + (quad >> 1)) ^ (l & 7);
            *(uint2*)&sE[l * 64 + gph * 8 + (quad & 1) * 4] =
                make_uint2(cvtpk(p0, p1), cvtpk(p2, p3));
            *(uint2*)&sMg[l * 64 + gph * 8 + (quad & 1) * 4] =
                make_uint2(cvtpk(mg0, mg1), cvtpk(mg2, mg3));
        }
        {
            bf16x8 mf0 = ldfrag(sMg, w * 16 + lo16, quad);
            bf16x8 mf1 = ldfrag(sMg, w * 16 + lo16, quad + 4);
            bf16x8 b0 = (bf16x8){0, 0, 0, 0, 0, 0, 0, 0};
            bf16x8 b1 = (bf16x8){0, 0, 0, 0, 0, 0, 0, 0};
            if (lo16 < 4) {
                b0 = *(const bf16x8*)&sAmb[lo16 * 1032 + m0 + quad * 8];
                b1 = *(const bf16x8*)&sAmb[lo16 * 1032 + m0 + 32 + quad * 8];
            }
            accM1 = MFMA(mf0, b0, accM1);
            accM1 = MFMA(mf1, b1, accM1);
        }
        if (mt < 15) {
            asm volatile("s_waitcnt vmcnt(4)" ::: "memory");
        } else {
            asm volatile("s_waitcnt vmcnt(0)" ::: "memory");
        }
        __builtin_amdgcn_s_barrier();
        {
            bf16x8 pa0 = ldfrag(sE, w * 16 + lo16, quad);
            bf16x8 pa1 = ldfrag(sE, w * 16 + lo16, quad + 4);
            __builtin_amdgcn_s_setprio(1);
#pragma unroll
            for (int dt = 0; dt < 4; ++dt) {
                int dr = dt * 16 + lo16;
                bf16x8 vr0 = ldfrag(sV0, dr, quad), vr1 = ldfrag(sV0, dr, quad + 4);
                bf16x8 vi0 = ldfrag(sV1, dr, quad), vi1 = ldfrag(sV1, dr, quad + 4);
                aOutR[dt] = MFMA(pa0, vr0, aOutR[dt]);
                aOutR[dt] = MFMA(pa1, vr1, aOutR[dt]);
                aOutI[dt] = MFMA(pa0, vi0, aOutI[dt]);
                aOutI[dt] = MFMA(pa1, vi1, aOutI[dt]);
            }
            __builtin_amdgcn_s_setprio(0);
        }
        asm volatile("s_waitcnt vmcnt(0)" ::: "memory");
        __builtin_amdgcn_s_barrier();
    }

    if (lo16 < 4) {
#pragma unroll
        for (int reg = 0; reg < 4; ++reg) {
            int r = w * 16 + quad * 4 + reg;
            float alv = b2f(sAmb[lo16 * 1032 + (l0 + r)]) * 8.0f;
            sDen[lo16 * 64 + r] = 1.0f / (1024.0f + alv * accM1[reg]);
        }
    }
    float cden[4];
#pragma unroll
    for (int reg = 0; reg < 4; ++reg) {
        int r = w * 16 + quad * 4 + reg;
        cden[reg] = sDen[r] + sDen[64 + r] + sDen[128 + r] + sDen[192 + r];
    }

    const float cE = rsqrtf(2048.0f) * rsqrtf(24.0f);
    float eRr[4], eRi[4];
#pragma unroll
    for (int reg = 0; reg < 4; ++reg) {
        int lrow = l0 + w * 16 + quad * 4 + reg;
        float tl = (2.0f * PI_F / (float)(LMAX_ - 1)) * (float)lrow;
        float s1, c1;
        __sincosf(0.1f * tl, &s1, &c1);
        const float W[10] = {1.f, 2.f, 3.f, 3.f, 3.f, 3.f, 3.f, 3.f, 2.f, 1.f};
        float cr = c1, ci = s1;
        float er = W[0] * cr, ei = W[0] * ci;
#pragma unroll
        for (int k = 1; k < 10; ++k) {
            float nr = cr * c1 - ci * s1;
            float ni = cr * s1 + ci * c1;
            cr = nr; ci = ni;
            er = fmaf(W[k], cr, er);
            ei = fmaf(W[k], ci, ei);
        }
        eRr[reg] = er * cE;
        eRi[reg] = ei * cE;
    }

    const size_t ooff = (size_t)BH_ * L_ * D_;
#pragma unroll
    for (int dt = 0; dt < 4; ++dt) {
        int d = dt * 16 + lo16;
        const float* svp = ws + WS_SVP + bh * 1024 + (size_t)d * 16;
        float4 r0 = *(const float4*)(svp);
        float4 r1 = *(const float4*)(svp + 4);
        float4 r2 = *(const float4*)(svp + 8);
        float4 r3 = *(const float4*)(svp + 12);
        float svr = (r0.x + r0.y + r0.z + r0.w) + (r1.x + r1.y + r1.z + r1.w) +
                    (r2.x + r2.y + r2.z + r2.w) + (r3.x + r3.y + r3.z + r3.w);
        const float* svq = svp + 32768;
        r0 = *(const float4*)(svq);
        r1 = *(const float4*)(svq + 4);
        r2 = *(const float4*)(svq + 8);
        r3 = *(const float4*)(svq + 12);
        float svi = (r0.x + r0.y + r0.z + r0.w) + (r1.x + r1.y + r1.z + r1.w) +
                    (r2.x + r2.y + r2.z + r2.w) + (r3.x + r3.y + r3.z + r3.w);
        float sp, cp;
        __sincosf((2.0f * PI_F / 64.0f) * (float)d, &sp, &cp);
#pragma unroll
        for (int reg = 0; reg < 4; ++reg) {
            int lrow = l0 + w * 16 + quad * 4 + reg;
            float numR = fmaf(cden[reg], svr, aOutR[dt][reg]) * 0.5f;
            float numI = fmaf(cden[reg], svi, aOutI[dt][reg]) * 0.5f;
            float epr = cp * eRr[reg] - sp * eRi[reg];
            float epi = sp * eRr[reg] + cp * eRi[reg];
            size_t o = base + (size_t)lrow * 64 + d;
            out[o] = numR * epr - numI * epi;
            out[o + ooff] = numR * epi + numI * epr;
        }
    }
}

extern "C" void kernel_launch(void* const* d_in, const int* in_sizes, int n_in,
                              void* d_out, int out_size, void* d_ws, size_t ws_size,
                              hipStream_t stream) {
    const float* Qr = (const float*)d_in[0];
    const float* Qi = (const float*)d_in[1];
    const float* Kr = (const float*)d_in[2];
    const float* Ki = (const float*)d_in[3];
    const float* Vr = (const float*)d_in[4];
    const float* Vi = (const float*)d_in[5];
    float* ws = (float*)d_ws;
    float* out = (float*)d_out;

    const double fr[4] = {1.0, 0.5, 0.25, 0.1};
    float inv[4];
    for (int s = 0; s < 4; ++s) {
        double a = 2.0 * 3.14159265358979323846 * fr[s] / (double)(LMAX_ - 1);
        double S = 3.0 * LMAX_;
        const double mul[3] = {1.0, 0.5, 1.5};
        for (int k = 0; k < 3; ++k) {
            double x = a * mul[k];
            S += 2.0 * (cos(x * 1023.5) * sin(x * 1024.0) / sin(x * 0.5));
        }
        inv[s] = (float)(1.0 / sqrt(S));
    }
    float4 invn = make_float4(inv[0], inv[1], inv[2], inv[3]);

    prep_kernel<<<1280, BDIM, 0, stream>>>(Kr, Ki, Vr, Vi, ws);

    // wide attn needs 141,376 B dynamic LDS (>64K static limit)
    static int wideOK = -1;
    if (wideOK < 0) {
        hipError_t e = hipFuncSetAttribute(
            reinterpret_cast<const void*>(attn_kernel_w),
            hipFuncAttributeMaxDynamicSharedMemorySize, SMEM_BYTES);
        wideOK = (e == hipSuccess) ? 1 : 0;
    }
    if (wideOK)
        attn_kernel_w<<<256, ADIM, SMEM_BYTES, stream>>>(Qr, Qi, ws, out, invn);
    else
        attn_kernel<<<512, BDIM, 0, stream>>>(Qr, Qi, ws, out, invn);
}

// Round 10
// 134.587 us; speedup vs baseline: 1.0344x; 1.0344x over previous
//
#include <hip/hip_runtime.h>
#include <math.h>

typedef short bf16x8 __attribute__((ext_vector_type(8)));
typedef float f32x4 __attribute__((ext_vector_type(4)));

#define BDIM 256     // prep + fallback attn
#define ADIM 1024    // wide attn (16 waves, m-split)
constexpr int B_ = 2, H_ = 16, L_ = 1024, D_ = 64, LMAX_ = 2048;
constexpr int BH_ = B_ * H_;
constexpr float PI_F = 3.14159265358979323846f;

// ws float offsets
constexpr int WS_SVP = 0;                    // fp32 [2][32][64][16] SumV partials ([d][q])
constexpr int WS_KBR = 65536;                // u16 [32][1024][64]
constexpr int WS_KBI = WS_KBR + 1048576;
constexpr int WS_VTR = WS_KBI + 1048576;     // u16 [32][64][1024]
constexpr int WS_VTI = WS_VTR + 1048576;

__device__ __forceinline__ unsigned short f2b(float x) {
    union { float f; unsigned u; } v; v.f = x;
    return (unsigned short)((v.u + 0x8000u) >> 16);
}
__device__ __forceinline__ float b2f(unsigned short x) {
    union { unsigned u; float f; } v; v.u = ((unsigned)x) << 16;
    return v.f;
}
__device__ __forceinline__ unsigned pk2(float a, float b) {
    union { float f; unsigned u; } va, vb; va.f = a; vb.f = b;
    return ((va.u + 0x8000u) >> 16) | ((vb.u + 0x8000u) & 0xFFFF0000u);
}
__device__ __forceinline__ uint4 pack4(const float4& a, const float4& b) {
    return make_uint4(pk2(a.x, a.y), pk2(a.z, a.w), pk2(b.x, b.y), pk2(b.z, b.w));
}
__device__ __forceinline__ unsigned cvtpk(float lo, float hi) {
    unsigned r;
    asm("v_cvt_pk_bf16_f32 %0, %1, %2" : "=v"(r) : "v"(lo), "v"(hi));
    return r;
}
__device__ __forceinline__ float vsqrt(float x) {
    float r;
    asm("v_sqrt_f32 %0, %1" : "=v"(r) : "v"(x));
    return r;
}

#define MFMA(a, b, c) __builtin_amdgcn_mfma_f32_16x16x32_bf16((a), (b), (c), 0, 0, 0)

__device__ __forceinline__ float a_val(int s, int l, float4 invn) {
    const float fr = (s == 0) ? 1.0f : (s == 1) ? 0.5f : (s == 2) ? 0.25f : 0.1f;
    const float iv = (s == 0) ? invn.x : (s == 1) ? invn.y : (s == 2) ? invn.z : invn.w;
    float t = (2.0f * PI_F * fr / (float)(LMAX_ - 1)) * (float)l;
    float m2 = 3.0f + 2.0f * cosf(t) + 2.0f * cosf(0.5f * t) + 2.0f * cosf(1.5f * t);
    return sqrtf(fmaxf(m2, 0.0f)) * iv;
}

// ---------------- prep: K->bf16, V->V^T bf16, SumV partials ----------------
__global__ __launch_bounds__(BDIM)
void prep_kernel(const float* __restrict__ Kr, const float* __restrict__ Ki,
                 const float* __restrict__ Vr, const float* __restrict__ Vi,
                 float* __restrict__ ws) {
    const int tid = threadIdx.x;
    const int blk = blockIdx.x;
    unsigned short* KbR = (unsigned short*)(ws + WS_KBR);
    unsigned short* KbI = (unsigned short*)(ws + WS_KBI);
    unsigned short* VtR = (unsigned short*)(ws + WS_VTR);
    unsigned short* VtI = (unsigned short*)(ws + WS_VTI);

    if (blk < 256) {
        const int comp = blk >> 7;
        const float* src = comp ? Ki : Kr;
        unsigned short* dst = comp ? KbI : KbR;
        size_t b0 = (size_t)(blk & 127) * 16384;
#pragma unroll
        for (int i = 0; i < 4; ++i) {
            size_t e = b0 + (size_t)(i * 256 + tid) * 16;
            float4 x0 = *(const float4*)(src + e);
            float4 x1 = *(const float4*)(src + e + 4);
            float4 x2 = *(const float4*)(src + e + 8);
            float4 x3 = *(const float4*)(src + e + 12);
            *(uint4*)(dst + e) = pack4(x0, x1);
            *(uint4*)(dst + e + 8) = pack4(x2, x3);
        }
    } else {
        // sT stride 70 (35 dwords == 3 mod 32): conflict-free writes, ~2-way reads
        __shared__ unsigned short sT[64 * 70];
        __shared__ float sRed[4 * 64];
        const int vb = blk - 256;
        const int comp = vb & 1, mt = (vb >> 1) & 15, bh = vb >> 5;
        const int m0 = mt * 64;
        const float* src = (comp ? Vi : Vr) + (size_t)bh * 65536 + (size_t)m0 * 64;
        unsigned short* dstA = (comp ? VtI : VtR) + (size_t)bh * 65536;
#pragma unroll
        for (int i = 0; i < 4; ++i) {
            int e = i * 256 + tid;
            int m = e >> 4, d4 = (e & 15) * 4;
            float4 x = *(const float4*)(src + (size_t)m * 64 + d4);
            *(uint2*)&sT[m * 70 + d4] = make_uint2(pk2(x.x, x.y), pk2(x.z, x.w));
        }
        {
            int d = tid & 63, grp = tid >> 6;
            float s = 0.0f;
#pragma unroll
            for (int k = 0; k < 16; ++k) s += src[(size_t)(grp * 16 + k) * 64 + d];
            sRed[grp * 64 + d] = s;
        }
        __syncthreads();
        {
            int d = tid >> 2, ms = (tid & 3) * 16;
            unsigned short v[16];
#pragma unroll
            for (int k = 0; k < 16; ++k) v[k] = sT[(ms + k) * 70 + d];
            unsigned short* dst = dstA + (size_t)d * 1024 + m0 + ms;
            *(uint4*)dst = make_uint4((unsigned)v[0] | ((unsigned)v[1] << 16),
                                      (unsigned)v[2] | ((unsigned)v[3] << 16),
                                      (unsigned)v[4] | ((unsigned)v[5] << 16),
                                      (unsigned)v[6] | ((unsigned)v[7] << 16));
            *(uint4*)(dst + 8) = make_uint4((unsigned)v[8] | ((unsigned)v[9] << 16),
                                            (unsigned)v[10] | ((unsigned)v[11] << 16),
                                            (unsigned)v[12] | ((unsigned)v[13] << 16),
                                            (unsigned)v[14] | ((unsigned)v[15] << 16));
        }
        if (tid < 64)
            ws[WS_SVP + comp * 32768 + bh * 1024 + tid * 16 + mt] =
                sRed[tid] + sRed[64 + tid] + sRed[128 + tid] + sRed[192 + tid];
    }
}

// ---------------- staging / fragment helpers ----------------
__device__ __forceinline__ void stage64s(const unsigned short* g0, int stride,
                                         unsigned short* lds, int w, int lane) {
#pragma unroll
    for (int i = 0; i < 2; ++i) {
        int c = w * 2 + i;
        int lrow = c * 8 + (lane >> 3);
        int lg = (lane & 7) ^ (lrow & 7);
        const unsigned short* src = g0 + (size_t)lrow * stride + lg * 8;
        __builtin_amdgcn_global_load_lds(
            (const __attribute__((address_space(1))) void*)src,
            (__attribute__((address_space(3))) void*)(lds + c * 512), 16, 0, 0);
    }
}
__device__ __forceinline__ bf16x8 ldfrag(const unsigned short* b, int row, int g) {
    return *(const bf16x8*)&b[row * 64 + ((g ^ (row & 7)) << 3)];
}

// ---------------- wide attention: 16 waves, m-split across wave pairs ----------------
// Round-9 was FLAT -> idle is not fillable intra-wave ILP. LDS stream ~340 KB/
// CU/iter (~50% busy) + only 2 waves/SIMD -> latency exposure. Fix: double TLP
// at CONSTANT traffic. 1024-thread blocks, wave (half=w>>3, w8=w&7): same 16
// q-rows (w8) but only m-half [half*32, half*32+32). Fragment layouts already
// partition by half (pa0/pa1, vr0/vr1, mf0/mf1, ct 0-1/2-3 = g index quad vs
// quad+4), so the split is index arithmetic; sE/sMg rows stay wave-private per
// half. Per-wave work/traffic halves; per-CU constant; 4 waves/SIMD.
// Epilogue: half-1 writes aOut/accM1 to dead K/V/E LDS; barrier; half-0 adds.
constexpr int OFF_DEN = 0;                        // f32 [4][128]      2048 B
constexpr int OFF_K0  = 2048;                     // u16 [2][4096]    16384 B
constexpr int OFF_K1  = OFF_K0 + 16384;
constexpr int OFF_V0  = OFF_K1 + 16384;           // u16 [2][4096]    16384 B
constexpr int OFF_V1  = OFF_V0 + 16384;
constexpr int OFF_E   = OFF_V1 + 16384;           // u16 [128*64]     16384 B
constexpr int OFF_MG  = OFF_E + 16384;
constexpr int OFF_AMB = OFF_MG + 16384;           // u16 [4*1032]      8256 B
constexpr int SMEM_BYTES = OFF_AMB + 8256;        // = 108608

__global__ __launch_bounds__(ADIM, 1)
void attn_kernel_w(const float* __restrict__ Qr, const float* __restrict__ Qi,
                   const float* __restrict__ ws, float* __restrict__ out, float4 invn) {
    extern __shared__ char smem[];
    float* sDen = (float*)(smem + OFF_DEN);
    unsigned short* sK0 = (unsigned short*)(smem + OFF_K0);   // [2][4096]
    unsigned short* sK1 = (unsigned short*)(smem + OFF_K1);
    unsigned short* sV0 = (unsigned short*)(smem + OFF_V0);   // [2][4096]
    unsigned short* sV1 = (unsigned short*)(smem + OFF_V1);
    unsigned short* sE  = (unsigned short*)(smem + OFF_E);    // [128][64]
    unsigned short* sMg = (unsigned short*)(smem + OFF_MG);
    unsigned short* sAmb = (unsigned short*)(smem + OFF_AMB); // stride 1032

    const int tid = threadIdx.x;
    const int lane = tid & 63;
    const int w = tid >> 6;                     // 0..15
    const int half = w >> 3;                    // m-half this wave owns
    const int w8 = w & 7;                       // l-group (16 q-rows)
    const int lo16 = lane & 15;
    const int quad = lane >> 4;
    const int gh = quad + half * 4;             // ldfrag g-index for this half
    const int blk = blockIdx.x;                 // 256 blocks
    const int bh = (blk & 7) * 4 + (blk >> 6);  // XCD-clustered
    const int qt = (blk >> 3) & 7;
    const int l0 = qt * 128;
    const size_t base = (size_t)bh * (L_ * D_);

    const unsigned short* gKr = (const unsigned short*)(ws + WS_KBR) + (size_t)bh * 65536;
    const unsigned short* gKi = (const unsigned short*)(ws + WS_KBI) + (size_t)bh * 65536;
    const unsigned short* gVr = (const unsigned short*)(ws + WS_VTR) + (size_t)bh * 65536;
    const unsigned short* gVi = (const unsigned short*)(ws + WS_VTI) + (size_t)bh * 65536;

    // prologue staging: waves 0-3 K(0), waves 8-11 V(0)
    if (w < 4) {
        stage64s(gKr, 64, sK0, w, lane);
        stage64s(gKi, 64, sK1, w, lane);
    } else if (w >= 8 && w < 12) {
        stage64s(gVr, 1024, sV0, w - 8, lane);
        stage64s(gVi, 1024, sV1, w - 8, lane);
    }

    // amb table (a/8 bf16)
    for (int e = tid; e < 4096; e += ADIM) {
        int s = e >> 10, l = e & 1023;
        sAmb[s * 1032 + l] = f2b(a_val(s, l, invn) * 0.125f);
    }

    // Q fragments (same for both halves of a pair; 2nd read L2-hits)
    bf16x8 fQr0, fQr1, fQi0, fQi1, fnQi0, fnQi1;
    {
        const int ql = l0 + w8 * 16 + lo16;
        const float* qr = Qr + base + (size_t)ql * 64;
        const float* qi = Qi + base + (size_t)ql * 64;
        float4 a0 = *(const float4*)(qr + quad * 8);
        float4 a1 = *(const float4*)(qr + quad * 8 + 4);
        float4 b0 = *(const float4*)(qr + 32 + quad * 8);
        float4 b1 = *(const float4*)(qr + 32 + quad * 8 + 4);
        *(uint4*)&fQr0 = pack4(a0, a1);
        *(uint4*)&fQr1 = pack4(b0, b1);
        a0 = *(const float4*)(qi + quad * 8);
        a1 = *(const float4*)(qi + quad * 8 + 4);
        b0 = *(const float4*)(qi + 32 + quad * 8);
        b1 = *(const float4*)(qi + 32 + quad * 8 + 4);
        *(uint4*)&fQi0 = pack4(a0, a1);
        *(uint4*)&fQi1 = pack4(b0, b1);
        uint4 t0 = *(uint4*)&fQi0, t1 = *(uint4*)&fQi1;
        t0.x ^= 0x80008000u; t0.y ^= 0x80008000u; t0.z ^= 0x80008000u; t0.w ^= 0x80008000u;
        t1.x ^= 0x80008000u; t1.y ^= 0x80008000u; t1.z ^= 0x80008000u; t1.w ^= 0x80008000u;
        *(uint4*)&fnQi0 = t0; *(uint4*)&fnQi1 = t1;
    }

    __syncthreads();   // tile-0 + sAmb visible

    bf16x8 uf1a = (bf16x8){0, 0, 0, 0, 0, 0, 0, 0};
    uf1a[0] = (short)f2b(b2f(sAmb[quad * 1032 + (l0 + w8 * 16 + lo16)]) *
                         (1.0f / 128.0f));

    f32x4 accM1 = (f32x4){0.f, 0.f, 0.f, 0.f};
    f32x4 aOutR[4], aOutI[4];
#pragma unroll
    for (int dt = 0; dt < 4; ++dt) {
        aOutR[dt] = (f32x4){0.f, 0.f, 0.f, 0.f};
        aOutI[dt] = (f32x4){0.f, 0.f, 0.f, 0.f};
    }

    const int lrow_w = w8 * 16 + lo16;   // this wave's row in sE/sMg

#pragma unroll 1
    for (int mt = 0; mt < 16; ++mt) {
        const int m0 = mt * 64;
        const int cur = mt & 1;
        // stage tile mt+1 into slot cur^1 (published by this iter's end barrier)
        if (mt < 15) {
            if (w < 4) {
                stage64s(gKr + (size_t)(m0 + 64) * 64, 64, sK0 + (cur ^ 1) * 4096, w, lane);
                stage64s(gKi + (size_t)(m0 + 64) * 64, 64, sK1 + (cur ^ 1) * 4096, w, lane);
            } else if (w >= 8 && w < 12) {
                stage64s(gVr + m0 + 64, 1024, sV0 + (cur ^ 1) * 4096, w - 8, lane);
                stage64s(gVi + m0 + 64, 1024, sV1 + (cur ^ 1) * 4096, w - 8, lane);
            }
        }
        const unsigned short* cK0 = sK0 + cur * 4096;
        const unsigned short* cK1 = sK1 + cur * 4096;
        const unsigned short* cV0 = sV0 + cur * 4096;
        const unsigned short* cV1 = sV1 + cur * 4096;

        // QK^T for this wave's m-half: ct_eff = half*2 + {0,1}
#pragma unroll
        for (int ct = 0; ct < 2; ++ct) {
            const int ct_eff = half * 2 + ct;
            const int mrow = ct_eff * 16 + lo16;
            bf16x8 kr0 = ldfrag(cK0, mrow, quad), kr1 = ldfrag(cK0, mrow, quad + 4);
            bf16x8 ki0 = ldfrag(cK1, mrow, quad), ki1 = ldfrag(cK1, mrow, quad + 4);
            f32x4 aR = (f32x4){0.f, 0.f, 0.f, 0.f};
            f32x4 aI = (f32x4){0.f, 0.f, 0.f, 0.f};
            __builtin_amdgcn_s_setprio(1);
            aR = MFMA(kr0, fQr0, aR);  aR = MFMA(kr1, fQr1, aR);   // S^T = K·Q^T
            aR = MFMA(ki0, fnQi0, aR); aR = MFMA(ki1, fnQi1, aR);
            aI = MFMA(ki0, fQr0, aI);  aI = MFMA(ki1, fQr1, aI);
            aI = MFMA(kr0, fQi0, aI);  aI = MFMA(kr1, fQi1, aI);
            __builtin_amdgcn_s_setprio(0);
            float mg0 = vsqrt(fmaf(aR[0], aR[0], aI[0] * aI[0]));
            float mg1 = vsqrt(fmaf(aR[1], aR[1], aI[1] * aI[1]));
            float mg2 = vsqrt(fmaf(aR[2], aR[2], aI[2] * aI[2]));
            float mg3 = vsqrt(fmaf(aR[3], aR[3], aI[3] * aI[3]));
            bf16x8 bf1 = (bf16x8){0, 0, 0, 0, 0, 0, 0, 0};
            bf1[0] = (short)sAmb[quad * 1032 + m0 + ct_eff * 16 + lo16];
            f32x4 z = (f32x4){0.f, 0.f, 0.f, 0.f};
            f32x4 a1 = MFMA(bf1, uf1a, z);
            float p0 = mg0 * a1[0], p1 = mg1 * a1[1];
            float p2 = mg2 * a1[2], p3 = mg3 * a1[3];
            int gph = (ct_eff * 2 + (quad >> 1)) ^ (lrow_w & 7);
            *(uint2*)&sE[lrow_w * 64 + gph * 8 + (quad & 1) * 4] =
                make_uint2(cvtpk(p0, p1), cvtpk(p2, p3));
            *(uint2*)&sMg[lrow_w * 64 + gph * 8 + (quad & 1) * 4] =
                make_uint2(cvtpk(mg0, mg1), cvtpk(mg2, mg3));
        }
        // M1 matvec, this half only (mf covers m-half via gh)
        {
            bf16x8 mf = ldfrag(sMg, lrow_w, gh);
            bf16x8 b0 = (bf16x8){0, 0, 0, 0, 0, 0, 0, 0};
            if (lo16 < 4)
                b0 = *(const bf16x8*)&sAmb[lo16 * 1032 + m0 + half * 32 + quad * 8];
            accM1 = MFMA(mf, b0, accM1);
        }
        // PV, this half only (pa/v fragments at g = quad + half*4)
        {
            bf16x8 pa = ldfrag(sE, lrow_w, gh);
            __builtin_amdgcn_s_setprio(1);
#pragma unroll
            for (int dt = 0; dt < 4; ++dt) {
                int dr = dt * 16 + lo16;
                bf16x8 vr = ldfrag(cV0, dr, gh);
                bf16x8 vi = ldfrag(cV1, dr, gh);
                aOutR[dt] = MFMA(pa, vr, aOutR[dt]);
                aOutI[dt] = MFMA(pa, vi, aOutI[dt]);
            }
            __builtin_amdgcn_s_setprio(0);
        }
        // stagers drain own loads (a full compute phase old); others free
        asm volatile("s_waitcnt vmcnt(0)" ::: "memory");
        __builtin_amdgcn_s_barrier();
    }

    // ---- cross-half reduction: half-1 -> LDS scratch (dead K/V/E region) ----
    char* scr = smem + OFF_K0;   // 2048..75776 < OFF_MG; K/V/E dead after loop
    if (half == 1) {
#pragma unroll
        for (int dt = 0; dt < 4; ++dt) {
            *(f32x4*)(scr + w8 * 9216 + dt * 1024 + lane * 16) = aOutR[dt];
            *(f32x4*)(scr + w8 * 9216 + 4096 + dt * 1024 + lane * 16) = aOutI[dt];
        }
        *(f32x4*)(scr + w8 * 9216 + 8192 + lane * 16) = accM1;
    }
    __syncthreads();
    if (half == 1) return;   // after the barrier: safe

#pragma unroll
    for (int dt = 0; dt < 4; ++dt) {
        aOutR[dt] += *(const f32x4*)(scr + w8 * 9216 + dt * 1024 + lane * 16);
        aOutI[dt] += *(const f32x4*)(scr + w8 * 9216 + 4096 + dt * 1024 + lane * 16);
    }
    accM1 += *(const f32x4*)(scr + w8 * 9216 + 8192 + lane * 16);

    // exact denominators (same-wave rows)
    if (lo16 < 4) {
#pragma unroll
        for (int reg = 0; reg < 4; ++reg) {
            int r = w8 * 16 + quad * 4 + reg;
            float alv = b2f(sAmb[lo16 * 1032 + (l0 + r)]) * 8.0f;
            sDen[lo16 * 128 + r] = 1.0f / (1024.0f + alv * accM1[reg]);
        }
    }
    float cden[4];
#pragma unroll
    for (int reg = 0; reg < 4; ++reg) {
        int r = w8 * 16 + quad * 4 + reg;   // same-wave LDS read
        cden[reg] = sDen[r] + sDen[128 + r] + sDen[256 + r] + sDen[384 + r];
    }

    // expert eC
    const float cE = rsqrtf(2048.0f) * rsqrtf(24.0f);
    float eRr[4], eRi[4];
#pragma unroll
    for (int reg = 0; reg < 4; ++reg) {
        int lrow = l0 + w8 * 16 + quad * 4 + reg;
        float tl = (2.0f * PI_F / (float)(LMAX_ - 1)) * (float)lrow;
        float s1, c1;
        __sincosf(0.1f * tl, &s1, &c1);
        const float W[10] = {1.f, 2.f, 3.f, 3.f, 3.f, 3.f, 3.f, 3.f, 2.f, 1.f};
        float cr = c1, ci = s1;
        float er = W[0] * cr, ei = W[0] * ci;
#pragma unroll
        for (int k = 1; k < 10; ++k) {
            float nr = cr * c1 - ci * s1;
            float ni = cr * s1 + ci * c1;
            cr = nr; ci = ni;
            er = fmaf(W[k], cr, er);
            ei = fmaf(W[k], ci, ei);
        }
        eRr[reg] = er * cE;
        eRi[reg] = ei * cE;
    }

    const size_t ooff = (size_t)BH_ * L_ * D_;
#pragma unroll
    for (int dt = 0; dt < 4; ++dt) {
        int d = dt * 16 + lo16;
        const float* svp = ws + WS_SVP + bh * 1024 + (size_t)d * 16;
        float4 r0 = *(const float4*)(svp);
        float4 r1 = *(const float4*)(svp + 4);
        float4 r2 = *(const float4*)(svp + 8);
        float4 r3 = *(const float4*)(svp + 12);
        float svr = (r0.x + r0.y + r0.z + r0.w) + (r1.x + r1.y + r1.z + r1.w) +
                    (r2.x + r2.y + r2.z + r2.w) + (r3.x + r3.y + r3.z + r3.w);
        const float* svq = svp + 32768;
        r0 = *(const float4*)(svq);
        r1 = *(const float4*)(svq + 4);
        r2 = *(const float4*)(svq + 8);
        r3 = *(const float4*)(svq + 12);
        float svi = (r0.x + r0.y + r0.z + r0.w) + (r1.x + r1.y + r1.z + r1.w) +
                    (r2.x + r2.y + r2.z + r2.w) + (r3.x + r3.y + r3.z + r3.w);
        float sp, cp;
        __sincosf((2.0f * PI_F / 64.0f) * (float)d, &sp, &cp);
#pragma unroll
        for (int reg = 0; reg < 4; ++reg) {
            int lrow = l0 + w8 * 16 + quad * 4 + reg;
            float numR = fmaf(cden[reg], svr, aOutR[dt][reg]) * 0.5f;
            float numI = fmaf(cden[reg], svi, aOutI[dt][reg]) * 0.5f;
            float epr = cp * eRr[reg] - sp * eRi[reg];
            float epi = sp * eRr[reg] + cp * eRi[reg];
            size_t o = base + (size_t)lrow * 64 + d;
            out[o] = numR * epr - numI * epi;
            out[o + ooff] = numR * epi + numI * epr;
        }
    }
}

// ---------------- fallback: round-5 256-thr attention (verbatim) ----------------
__global__ __launch_bounds__(BDIM, 2)
void attn_kernel(const float* __restrict__ Qr, const float* __restrict__ Qi,
                 const float* __restrict__ ws, float* __restrict__ out, float4 invn) {
    __shared__ unsigned short sK0[2][4096], sK1[2][4096];
    __shared__ unsigned short sV0[4096], sV1[4096];
    __shared__ unsigned short sE[4096];
    __shared__ unsigned short sMg[4096];
    __shared__ unsigned short sAmb[4 * 1032];
    __shared__ float sDen[4 * 64];

    const int tid = threadIdx.x;
    const int lane = tid & 63;
    const int w = tid >> 6;
    const int lo16 = lane & 15;
    const int quad = lane >> 4;
    const int blk = blockIdx.x;
    const int bh = (blk & 7) * 4 + (blk >> 7);
    const int qt = (blk >> 3) & 15;
    const int l0 = qt * 64;
    const size_t base = (size_t)bh * (L_ * D_);

    const unsigned short* gKr = (const unsigned short*)(ws + WS_KBR) + (size_t)bh * 65536;
    const unsigned short* gKi = (const unsigned short*)(ws + WS_KBI) + (size_t)bh * 65536;
    const unsigned short* gVr = (const unsigned short*)(ws + WS_VTR) + (size_t)bh * 65536;
    const unsigned short* gVi = (const unsigned short*)(ws + WS_VTI) + (size_t)bh * 65536;

    stage64s(gKr, 64, sK0[0], w, lane);
    stage64s(gKi, 64, sK1[0], w, lane);

    for (int e = tid; e < 4096; e += BDIM) {
        int s = e >> 10, l = e & 1023;
        sAmb[s * 1032 + l] = f2b(a_val(s, l, invn) * 0.125f);
    }

    bf16x8 fQr0, fQr1, fQi0, fQi1, fnQi0, fnQi1;
    {
        const int ql = l0 + w * 16 + lo16;
        const float* qr = Qr + base + (size_t)ql * 64;
        const float* qi = Qi + base + (size_t)ql * 64;
        float4 a0 = *(const float4*)(qr + quad * 8);
        float4 a1 = *(const float4*)(qr + quad * 8 + 4);
        float4 b0 = *(const float4*)(qr + 32 + quad * 8);
        float4 b1 = *(const float4*)(qr + 32 + quad * 8 + 4);
        *(uint4*)&fQr0 = pack4(a0, a1);
        *(uint4*)&fQr1 = pack4(b0, b1);
        a0 = *(const float4*)(qi + quad * 8);
        a1 = *(const float4*)(qi + quad * 8 + 4);
        b0 = *(const float4*)(qi + 32 + quad * 8);
        b1 = *(const float4*)(qi + 32 + quad * 8 + 4);
        *(uint4*)&fQi0 = pack4(a0, a1);
        *(uint4*)&fQi1 = pack4(b0, b1);
        uint4 t0 = *(uint4*)&fQi0, t1 = *(uint4*)&fQi1;
        t0.x ^= 0x80008000u; t0.y ^= 0x80008000u; t0.z ^= 0x80008000u; t0.w ^= 0x80008000u;
        t1.x ^= 0x80008000u; t1.y ^= 0x80008000u; t1.z ^= 0x80008000u; t1.w ^= 0x80008000u;
        *(uint4*)&fnQi0 = t0; *(uint4*)&fnQi1 = t1;
    }

    __syncthreads();

    bf16x8 uf1a = (bf16x8){0, 0, 0, 0, 0, 0, 0, 0};
    uf1a[0] = (short)f2b(b2f(sAmb[quad * 1032 + (l0 + w * 16 + lo16)]) *
                         (1.0f / 128.0f));

    f32x4 accM1 = (f32x4){0.f, 0.f, 0.f, 0.f};
    f32x4 aOutR[4], aOutI[4];
#pragma unroll
    for (int dt = 0; dt < 4; ++dt) {
        aOutR[dt] = (f32x4){0.f, 0.f, 0.f, 0.f};
        aOutI[dt] = (f32x4){0.f, 0.f, 0.f, 0.f};
    }

#pragma unroll 1
    for (int mt = 0; mt < 16; ++mt) {
        const int m0 = mt * 64;
        const int cur = mt & 1;
        stage64s(gVr + m0, 1024, sV0, w, lane);
        stage64s(gVi + m0, 1024, sV1, w, lane);
        if (mt < 15) {
            stage64s(gKr + (size_t)(m0 + 64) * 64, 64, sK0[cur ^ 1], w, lane);
            stage64s(gKi + (size_t)(m0 + 64) * 64, 64, sK1[cur ^ 1], w, lane);
        }
        const unsigned short* cK0 = sK0[cur];
        const unsigned short* cK1 = sK1[cur];

#pragma unroll
        for (int ct = 0; ct < 4; ++ct) {
            const int mrow = ct * 16 + lo16;
            bf16x8 kr0 = ldfrag(cK0, mrow, quad), kr1 = ldfrag(cK0, mrow, quad + 4);
            bf16x8 ki0 = ldfrag(cK1, mrow, quad), ki1 = ldfrag(cK1, mrow, quad + 4);
            f32x4 aR = (f32x4){0.f, 0.f, 0.f, 0.f};
            f32x4 aI = (f32x4){0.f, 0.f, 0.f, 0.f};
            __builtin_amdgcn_s_setprio(1);
            aR = MFMA(kr0, fQr0, aR);  aR = MFMA(kr1, fQr1, aR);
            aR = MFMA(ki0, fnQi0, aR); aR = MFMA(ki1, fnQi1, aR);
            aI = MFMA(ki0, fQr0, aI);  aI = MFMA(ki1, fQr1, aI);
            aI = MFMA(kr0, fQi0, aI);  aI = MFMA(kr1, fQi1, aI);
            __builtin_amdgcn_s_setprio(0);
            float mg0 = vsqrt(fmaf(aR[0], aR[0], aI[0] * aI[0]));
            float mg1 = vsqrt(fmaf(aR[1], aR[1], aI[1] * aI[1]));
            float mg2 = vsqrt(fmaf(aR[2], aR[2], aI[2] * aI[2]));
            float mg3 = vsqrt(fmaf(aR[3], aR[3], aI[3] * aI[3]));
            bf16x8 bf1 = (bf16x8){0, 0, 0, 0, 0, 0, 0, 0};
            bf1[0] = (short)sAmb[quad * 1032 + m0 + ct * 16 + lo16];
            f32x4 z = (f32x4){0.f, 0.f, 0.f, 0.f};
            f32x4 a1 = MFMA(bf1, uf1a, z);
            float p0 = mg0 * a1[0], p1 = mg1 * a1[1];
            float p2 = mg2 * a1[2], p3 = mg3 * a1[3];
            int l = w * 16 + lo16;
            int gph = (ct * 2 + (quad >> 1)) ^ (l & 7);
            *(uint2*)&sE[l * 64 + gph * 8 + (quad & 1) * 4] =
                make_uint2(cvtpk(p0, p1), cvtpk(p2, p3));
            *(uint2*)&sMg[l * 64 + gph * 8 + (quad & 1) * 4] =
                make_uint2(cvtpk(mg0, mg1), cvtpk(mg2, mg3));
        }
        {
            bf16x8 mf0 = ldfrag(sMg, w * 16 + lo16, quad);
            bf16x8 mf1 = ldfrag(sMg, w * 16 + lo16, quad + 4);
            bf16x8 b0 = (bf16x8){0, 0, 0, 0, 0, 0, 0, 0};
            bf16x8 b1 = (bf16x8){0, 0, 0, 0, 0, 0, 0, 0};
            if (lo16 < 4) {
                b0 = *(const bf16x8*)&sAmb[lo16 * 1032 + m0 + quad * 8];
                b1 = *(const bf16x8*)&sAmb[lo16 * 1032 + m0 + 32 + quad * 8];
            }
            accM1 = MFMA(mf0, b0, accM1);
            accM1 = MFMA(mf1, b1, accM1);
        }
        if (mt < 15) {
            asm volatile("s_waitcnt vmcnt(4)" ::: "memory");
        } else {
            asm volatile("s_waitcnt vmcnt(0)" ::: "memory");
        }
        __builtin_amdgcn_s_barrier();
        {
            bf16x8 pa0 = ldfrag(sE, w * 16 + lo16, quad);
            bf16x8 pa1 = ldfrag(sE, w * 16 + lo16, quad + 4);
            __builtin_amdgcn_s_setprio(1);
#pragma unroll
            for (int dt = 0; dt < 4; ++dt) {
                int dr = dt * 16 + lo16;
                bf16x8 vr0 = ldfrag(sV0, dr, quad), vr1 = ldfrag(sV0, dr, quad + 4);
                bf16x8 vi0 = ldfrag(sV1, dr, quad), vi1 = ldfrag(sV1, dr, quad + 4);
                aOutR[dt] = MFMA(pa0, vr0, aOutR[dt]);
                aOutR[dt] = MFMA(pa1, vr1, aOutR[dt]);
                aOutI[dt] = MFMA(pa0, vi0, aOutI[dt]);
                aOutI[dt] = MFMA(pa1, vi1, aOutI[dt]);
            }
            __builtin_amdgcn_s_setprio(0);
        }
        asm volatile("s_waitcnt vmcnt(0)" ::: "memory");
        __builtin_amdgcn_s_barrier();
    }

    if (lo16 < 4) {
#pragma unroll
        for (int reg = 0; reg < 4; ++reg) {
            int r = w * 16 + quad * 4 + reg;
            float alv = b2f(sAmb[lo16 * 1032 + (l0 + r)]) * 8.0f;
            sDen[lo16 * 64 + r] = 1.0f / (1024.0f + alv * accM1[reg]);
        }
    }
    float cden[4];
#pragma unroll
    for (int reg = 0; reg < 4; ++reg) {
        int r = w * 16 + quad * 4 + reg;
        cden[reg] = sDen[r] + sDen[64 + r] + sDen[128 + r] + sDen[192 + r];
    }

    const float cE = rsqrtf(2048.0f) * rsqrtf(24.0f);
    float eRr[4], eRi[4];
#pragma unroll
    for (int reg = 0; reg < 4; ++reg) {
        int lrow = l0 + w * 16 + quad * 4 + reg;
        float tl = (2.0f * PI_F / (float)(LMAX_ - 1)) * (float)lrow;
        float s1, c1;
        __sincosf(0.1f * tl, &s1, &c1);
        const float W[10] = {1.f, 2.f, 3.f, 3.f, 3.f, 3.f, 3.f, 3.f, 2.f, 1.f};
        float cr = c1, ci = s1;
        float er = W[0] * cr, ei = W[0] * ci;
#pragma unroll
        for (int k = 1; k < 10; ++k) {
            float nr = cr * c1 - ci * s1;
            float ni = cr * s1 + ci * c1;
            cr = nr; ci = ni;
            er = fmaf(W[k], cr, er);
            ei = fmaf(W[k], ci, ei);
        }
        eRr[reg] = er * cE;
        eRi[reg] = ei * cE;
    }

    const size_t ooff = (size_t)BH_ * L_ * D_;
#pragma unroll
    for (int dt = 0; dt < 4; ++dt) {
        int d = dt * 16 + lo16;
        const float* svp = ws + WS_SVP + bh * 1024 + (size_t)d * 16;
        float4 r0 = *(const float4*)(svp);
        float4 r1 = *(const float4*)(svp + 4);
        float4 r2 = *(const float4*)(svp + 8);
        float4 r3 = *(const float4*)(svp + 12);
        float svr = (r0.x + r0.y + r0.z + r0.w) + (r1.x + r1.y + r1.z + r1.w) +
                    (r2.x + r2.y + r2.z + r2.w) + (r3.x + r3.y + r3.z + r3.w);
        const float* svq = svp + 32768;
        r0 = *(const float4*)(svq);
        r1 = *(const float4*)(svq + 4);
        r2 = *(const float4*)(svq + 8);
        r3 = *(const float4*)(svq + 12);
        float svi = (r0.x + r0.y + r0.z + r0.w) + (r1.x + r1.y + r1.z + r1.w) +
                    (r2.x + r2.y + r2.z + r2.w) + (r3.x + r3.y + r3.z + r3.w);
        float sp, cp;
        __sincosf((2.0f * PI_F / 64.0f) * (float)d, &sp, &cp);
#pragma unroll
        for (int reg = 0; reg < 4; ++reg) {
            int lrow = l0 + w * 16 + quad * 4 + reg;
            float numR = fmaf(cden[reg], svr, aOutR[dt][reg]) * 0.5f;
            float numI = fmaf(cden[reg], svi, aOutI[dt][reg]) * 0.5f;
            float epr = cp * eRr[reg] - sp * eRi[reg];
            float epi = sp * eRr[reg] + cp * eRi[reg];
            size_t o = base + (size_t)lrow * 64 + d;
            out[o] = numR * epr - numI * epi;
            out[o + ooff] = numR * epi + numI * epr;
        }
    }
}

extern "C" void kernel_launch(void* const* d_in, const int* in_sizes, int n_in,
                              void* d_out, int out_size, void* d_ws, size_t ws_size,
                              hipStream_t stream) {
    const float* Qr = (const float*)d_in[0];
    const float* Qi = (const float*)d_in[1];
    const float* Kr = (const float*)d_in[2];
    const float* Ki = (const float*)d_in[3];
    const float* Vr = (const float*)d_in[4];
    const float* Vi = (const float*)d_in[5];
    float* ws = (float*)d_ws;
    float* out = (float*)d_out;

    const double fr[4] = {1.0, 0.5, 0.25, 0.1};
    float inv[4];
    for (int s = 0; s < 4; ++s) {
        double a = 2.0 * 3.14159265358979323846 * fr[s] / (double)(LMAX_ - 1);
        double S = 3.0 * LMAX_;
        const double mul[3] = {1.0, 0.5, 1.5};
        for (int k = 0; k < 3; ++k) {
            double x = a * mul[k];
            S += 2.0 * (cos(x * 1023.5) * sin(x * 1024.0) / sin(x * 0.5));
        }
        inv[s] = (float)(1.0 / sqrt(S));
    }
    float4 invn = make_float4(inv[0], inv[1], inv[2], inv[3]);

    prep_kernel<<<1280, BDIM, 0, stream>>>(Kr, Ki, Vr, Vi, ws);

    // wide attn needs 108,608 B dynamic LDS (>64K static limit)
    static int wideOK = -1;
    if (wideOK < 0) {
        hipError_t e = hipFuncSetAttribute(
            reinterpret_cast<const void*>(attn_kernel_w),
            hipFuncAttributeMaxDynamicSharedMemorySize, SMEM_BYTES);
        wideOK = (e == hipSuccess) ? 1 : 0;
    }
    if (wideOK)
        attn_kernel_w<<<256, ADIM, SMEM_BYTES, stream>>>(Qr, Qi, ws, out, invn);
    else
        attn_kernel<<<512, BDIM, 0, stream>>>(Qr, Qi, ws, out, invn);
}